// Round 6
// baseline (146.794 us; speedup 1.0000x reference)
//
#include <hip/hip_runtime.h>

// phi = exp2(-S2*d2), S2 = 1/(2*ls^2*ln2) = 8.014973
// e = 2*S2*(x.c) - S2*|c|^2 - S2*|x|^2  =  a1*x + a2*y + a3*z + a4*1 + 1*PX
// via mfma_f32_16x16x32_bf16, split-bf16 (hi + residual-lo) features.
// SWAPPED operands (A=centers, B=points): D layout col=lane&15=point,
// row=(lane>>4)*4+reg=center -> exp2 + fp32 PV accumulation lane-local.
// R6: demand 2x waves (PT=2, 32 pts/block, 4 waves, 3125 blocks = 48.8
// waves/CU demanded; empirical rule: achieved ~ demand/2) + v_pk_fma_f32
// packed PV (f2 accumulators) + explicit next-tile register prefetch to
// take L2 latency off the wave critical path. Busy model: 663k iters x
// ~160cy -> ~43us issue floor; target elapsed ~50us (R5: 80.4, 40% idle).
#define S2 8.014973f
#define K2 16.029946f
#define ONEB ((unsigned short)0x3F80)  // bf16(1.0)
#define PT 2   // 16-point MFMA tiles per block
#define NW 4   // waves per block (center-split ways)

typedef float f32x4 __attribute__((ext_vector_type(4)));
typedef float f2 __attribute__((ext_vector_type(2)));
typedef short bf16x8 __attribute__((ext_vector_type(8)));

__device__ __forceinline__ unsigned short bhi(float v) {  // RNE f32->bf16
    unsigned int b = __builtin_bit_cast(unsigned int, v);
    return (unsigned short)((b + 0x7FFFu + ((b >> 16) & 1u)) >> 16);
}
__device__ __forceinline__ float bf2f(unsigned short h) {
    unsigned int u = ((unsigned int)h) << 16;
    return __builtin_bit_cast(float, u);
}

// One block (1 wave) per 16-center tile T: writes
//  afrag[T*64+lane] = A-fragment uint4 (8 bf16): row=lane&15, k=8*(lane>>4)+e
//  bpack[(T*12 + g*3 + comp)*4 + r] = coeff[comp][16T+4g+r] (D-layout floats)
__global__ void rbf_prep(const float* __restrict__ centers,
                         const float* __restrict__ cu,
                         const float* __restrict__ cv,
                         const float* __restrict__ cw,
                         uint4* __restrict__ afrag,
                         float* __restrict__ bpack, int M) {
    const int T = blockIdx.x;
    const int lane = threadIdx.x;
    const int row = lane & 15, g = lane >> 4;
    const int c = T * 16 + row;
    float cx = 0.f, cy = 0.f, cz = 0.f;
    if (c < M) { cx = centers[3*c]; cy = centers[3*c+1]; cz = centers[3*c+2]; }
    const float a1 = K2 * cx, a2 = K2 * cy, a3 = K2 * cz;
    const float a4 = -S2 * (cx*cx + cy*cy + cz*cz);
    const unsigned short a1h = bhi(a1), a2h = bhi(a2), a3h = bhi(a3), a4h = bhi(a4);
    const unsigned short a1l = bhi(a1 - bf2f(a1h));
    const unsigned short a2l = bhi(a2 - bf2f(a2h));
    const unsigned short a3l = bhi(a3 - bf2f(a3h));
    const unsigned short a4l = bhi(a4 - bf2f(a4h));
    const unsigned short F[16] = {a1h, a1h, a1l, a2h, a2h, a2l, a3h, a3h,
                                  a3l, a4h, a4l, ONEB, ONEB, 0, 0, 0};
    uint4 u;  // prep is tiny; scratch from dynamic F index is fine here
    u.x = (unsigned int)F[8*g+0] | ((unsigned int)F[8*g+1] << 16);
    u.y = (unsigned int)F[8*g+2] | ((unsigned int)F[8*g+3] << 16);
    u.z = (unsigned int)F[8*g+4] | ((unsigned int)F[8*g+5] << 16);
    u.w = (unsigned int)F[8*g+6] | ((unsigned int)F[8*g+7] << 16);
    afrag[T * 64 + lane] = u;

    if (lane < 48) {
        const int g2 = lane / 12, idx = lane % 12;
        const int comp = idx >> 2, r = idx & 3;
        const int c2 = T * 16 + g2 * 4 + r;
        float v = 0.f;  // padded centers get coeff 0 -> contribute nothing
        if (c2 < M)
            v = (comp == 0) ? cu[c2] : ((comp == 1) ? cv[c2] : cw[c2]);
        bpack[(T * 12 + g2 * 3 + comp) * 4 + r] = v;
    }
}

// Block = 256 thr = 4 waves; block owns 32 points (2 x 16-pt MFMA tiles).
// Wave w handles center tiles [w*per, (w+1)*per); LDS reduce across waves.
// grid = N/32 = 3125 blocks -> 12500 waves (48.8/CU demanded).
__global__ __launch_bounds__(256) void rbf_main(
        const float* __restrict__ x,
        const uint4* __restrict__ afrag,
        const float4* __restrict__ bpack4,
        float* __restrict__ out, int N, int NT) {
    __shared__ float acc[NW][32][3];

    const int tid = threadIdx.x;
    const int lane = tid & 63;
    const int w = __builtin_amdgcn_readfirstlane(tid >> 6);  // wave id
    const int col = lane & 15, g = lane >> 4;
    const int pb = blockIdx.x * (16 * PT);

    float xx[PT], xy[PT], xz[PT];
    bf16x8 bfrag[PT];
#pragma unroll
    for (int t = 0; t < PT; ++t) {
        const int p = pb + t * 16 + col;
        float a0 = 0.f, a1 = 0.f, a2 = 0.f;
        if (p < N) { a0 = x[3*p]; a1 = x[3*p+1]; a2 = x[3*p+2]; }
        xx[t] = a0; xy[t] = a1; xz[t] = a2;
        const float px = -S2 * (a0*a0 + a1*a1 + a2*a2);
        // B-fragment: col=lane&15=point, k=8*(lane>>4)+e. Point features:
        // [xh,xl,xh, yh,yl,yh, zh,zl,zh, 1,1, PXh,PXl, 0,0,0]
        const unsigned short xh = bhi(a0), yh = bhi(a1), zh = bhi(a2);
        const unsigned short xl = bhi(a0 - bf2f(xh));
        const unsigned short yl = bhi(a1 - bf2f(yh));
        const unsigned short zl = bhi(a2 - bf2f(zh));
        const unsigned short ph = bhi(px), pl = bhi(px - bf2f(ph));
        unsigned int b0 = 0, b1 = 0, b2 = 0, b3 = 0;
        if (g == 0) {            // k = 0..7
            b0 = (unsigned int)xh | ((unsigned int)xl << 16);
            b1 = (unsigned int)xh | ((unsigned int)yh << 16);
            b2 = (unsigned int)yl | ((unsigned int)yh << 16);
            b3 = (unsigned int)zh | ((unsigned int)zl << 16);
        } else if (g == 1) {     // k = 8..15
            b0 = (unsigned int)zh | ((unsigned int)ONEB << 16);
            b1 = (unsigned int)ONEB | ((unsigned int)ph << 16);
            b2 = (unsigned int)pl;  // (pl, 0)
            b3 = 0;
        }                         // g = 2,3: zero (k = 16..31 unused)
        uint4 bu_;
        bu_.x = b0; bu_.y = b1; bu_.z = b2; bu_.w = b3;
        bfrag[t] = __builtin_bit_cast(bf16x8, bu_);
    }

    const f32x4 zero = {0.f, 0.f, 0.f, 0.f};
    f2 AU[PT], AV[PT], AW[PT];
#pragma unroll
    for (int t = 0; t < PT; ++t) {
        AU[t] = (f2){0.f, 0.f}; AV[t] = (f2){0.f, 0.f}; AW[t] = (f2){0.f, 0.f};
    }

    const uint4* __restrict__ ap = afrag + lane;        // coalesced stream
    const float4* __restrict__ bp = bpack4 + g * 3;     // per-group 48B line

    // wave w owns center tiles [jb, je)
    const int per = (NT + NW - 1) / NW;
    const int jb = w * per;
    const int je = min(jb + per, NT);

    if (jb < je) {
        // software pipeline: regs hold tile T while T+1 is in flight
        uint4 a_c = ap[jb * 64];
        float4 bu_c = bp[jb * 12 + 0];
        float4 bv_c = bp[jb * 12 + 1];
        float4 bw_c = bp[jb * 12 + 2];
        for (int T = jb; T < je; ++T) {
            const int Tn = (T + 1 < je) ? T + 1 : T;   // cndmask, no branch
            const uint4 a_n = ap[Tn * 64];
            const float4 bu_n = bp[Tn * 12 + 0];
            const float4 bv_n = bp[Tn * 12 + 1];
            const float4 bw_n = bp[Tn * 12 + 2];

            const bf16x8 af = __builtin_bit_cast(bf16x8, a_c);
            const f2 BU01 = {bu_c.x, bu_c.y}, BU23 = {bu_c.z, bu_c.w};
            const f2 BV01 = {bv_c.x, bv_c.y}, BV23 = {bv_c.z, bv_c.w};
            const f2 BW01 = {bw_c.x, bw_c.y}, BW23 = {bw_c.z, bw_c.w};
#pragma unroll
            for (int t = 0; t < PT; ++t) {
                const f32x4 E = __builtin_amdgcn_mfma_f32_16x16x32_bf16(
                    af, bfrag[t], zero, 0, 0, 0);
                f2 P01, P23;
                P01.x = __builtin_amdgcn_exp2f(E[0]);
                P01.y = __builtin_amdgcn_exp2f(E[1]);
                P23.x = __builtin_amdgcn_exp2f(E[2]);
                P23.y = __builtin_amdgcn_exp2f(E[3]);
                AU[t] += P01 * BU01; AU[t] += P23 * BU23;  // v_pk_fma_f32
                AV[t] += P01 * BV01; AV[t] += P23 * BV23;
                AW[t] += P01 * BW01; AW[t] += P23 * BW23;
            }
            a_c = a_n; bu_c = bu_n; bv_c = bv_n; bw_c = bw_n;
        }
    }

    float au[PT], av[PT], aw[PT];
#pragma unroll
    for (int t = 0; t < PT; ++t) {
        au[t] = AU[t].x + AU[t].y;
        av[t] = AV[t].x + AV[t].y;
        aw[t] = AW[t].x + AW[t].y;
        // Reduce over the 4 lane groups g (centers {16T + 4g + r}).
        au[t] += __shfl_xor(au[t], 16); au[t] += __shfl_xor(au[t], 32);
        av[t] += __shfl_xor(av[t], 16); av[t] += __shfl_xor(av[t], 32);
        aw[t] += __shfl_xor(aw[t], 16); aw[t] += __shfl_xor(aw[t], 32);
    }

    // Base field once per point: wave 0 only.
    if (w == 0 && g == 0) {
#pragma unroll
        for (int t = 0; t < PT; ++t) {
            const float r = sqrtf(xx[t]*xx[t] + xy[t]*xy[t] + xz[t]*xz[t]);
            const float s = 1.f - r;
            au[t] = fmaf(xx[t], s, au[t]);
            av[t] = fmaf(xy[t], s, av[t]);
            aw[t] = fmaf(xz[t], s, aw[t]);
        }
    }

    if (g == 0) {
#pragma unroll
        for (int t = 0; t < PT; ++t) {
            acc[w][t * 16 + col][0] = au[t];
            acc[w][t * 16 + col][1] = av[t];
            acc[w][t * 16 + col][2] = aw[t];
        }
    }
    __syncthreads();

    // 96 outputs per block, stride-1 across tid -> coalesced store.
    if (tid < 96) {
        const int gi = pb * 3 + tid;
        if (gi < 3 * N) {
            const int pl = tid / 3, c = tid % 3;
            out[gi] = acc[0][pl][c] + acc[1][pl][c] +
                      acc[2][pl][c] + acc[3][pl][c];
        }
    }
}

extern "C" void kernel_launch(void* const* d_in, const int* in_sizes, int n_in,
                              void* d_out, int out_size, void* d_ws,
                              size_t ws_size, hipStream_t stream) {
    const float* x = (const float*)d_in[0];
    const float* centers = (const float*)d_in[1];
    const float* cu = (const float*)d_in[2];
    const float* cv = (const float*)d_in[3];
    const float* cw = (const float*)d_in[4];
    float* out = (float*)d_out;
    const int N = in_sizes[0] / 3;
    const int M = in_sizes[1] / 3;
    const int NT = (M + 15) / 16;

    uint4* afrag = (uint4*)d_ws;                              // NT*1024 B
    float* bpack = (float*)((char*)d_ws + (size_t)NT * 1024); // NT*192 B

    hipLaunchKernelGGL(rbf_prep, dim3(NT), dim3(64), 0, stream,
                       centers, cu, cv, cw, afrag, bpack, M);
    hipLaunchKernelGGL(rbf_main, dim3((N + 16 * PT - 1) / (16 * PT)),
                       dim3(256), 0, stream,
                       x, afrag, (const float4*)bpack, out, N, NT);
}

// Round 7
// 145.320 us; speedup vs baseline: 1.0101x; 1.0101x over previous
//
#include <hip/hip_runtime.h>

// phi = exp2(-S2*d2), S2 = 1/(2*ls^2*ln2) = 8.014973
// e = 2*S2*(x.c) - S2*|c|^2 - S2*|x|^2  =  a1*x + a2*y + a3*z + a4*1 + 1*PX
// via mfma_f32_16x16x32_bf16, split-bf16 (hi + residual-lo) features.
// SWAPPED operands (A=centers, B=points): D layout col=lane&15=point,
// row=(lane>>4)*4+reg=center -> exp2 + fp32 PV accumulation lane-local.
// R7 = R6's occupancy shape (PT=2, NW=4, 3125 blocks, 12500 waves -> 67%
// measured occupancy) x R5's scheduling (plain loop, compiler unroll, NO
// manual rotation -- R6's explicit pipeline forced a vmcnt drain per iter
// and regressed). pk_fma PV kept. Busy model ~44us (exp2=16cy empirical,
// 3 rounds calibrated); target elapsed ~60.
#define S2 8.014973f
#define K2 16.029946f
#define ONEB ((unsigned short)0x3F80)  // bf16(1.0)
#define PT 2   // 16-point MFMA tiles per block
#define NW 4   // waves per block (center-split ways)

typedef float f32x4 __attribute__((ext_vector_type(4)));
typedef float f2 __attribute__((ext_vector_type(2)));
typedef short bf16x8 __attribute__((ext_vector_type(8)));

__device__ __forceinline__ unsigned short bhi(float v) {  // RNE f32->bf16
    unsigned int b = __builtin_bit_cast(unsigned int, v);
    return (unsigned short)((b + 0x7FFFu + ((b >> 16) & 1u)) >> 16);
}
__device__ __forceinline__ float bf2f(unsigned short h) {
    unsigned int u = ((unsigned int)h) << 16;
    return __builtin_bit_cast(float, u);
}

// One block (1 wave) per 16-center tile T: writes
//  afrag[T*64+lane] = A-fragment uint4 (8 bf16): row=lane&15, k=8*(lane>>4)+e
//  bpack[(T*12 + g*3 + comp)*4 + r] = coeff[comp][16T+4g+r] (D-layout floats)
__global__ void rbf_prep(const float* __restrict__ centers,
                         const float* __restrict__ cu,
                         const float* __restrict__ cv,
                         const float* __restrict__ cw,
                         uint4* __restrict__ afrag,
                         float* __restrict__ bpack, int M) {
    const int T = blockIdx.x;
    const int lane = threadIdx.x;
    const int row = lane & 15, g = lane >> 4;
    const int c = T * 16 + row;
    float cx = 0.f, cy = 0.f, cz = 0.f;
    if (c < M) { cx = centers[3*c]; cy = centers[3*c+1]; cz = centers[3*c+2]; }
    const float a1 = K2 * cx, a2 = K2 * cy, a3 = K2 * cz;
    const float a4 = -S2 * (cx*cx + cy*cy + cz*cz);
    const unsigned short a1h = bhi(a1), a2h = bhi(a2), a3h = bhi(a3), a4h = bhi(a4);
    const unsigned short a1l = bhi(a1 - bf2f(a1h));
    const unsigned short a2l = bhi(a2 - bf2f(a2h));
    const unsigned short a3l = bhi(a3 - bf2f(a3h));
    const unsigned short a4l = bhi(a4 - bf2f(a4h));
    const unsigned short F[16] = {a1h, a1h, a1l, a2h, a2h, a2l, a3h, a3h,
                                  a3l, a4h, a4l, ONEB, ONEB, 0, 0, 0};
    uint4 u;  // prep is tiny; scratch from dynamic F index is fine here
    u.x = (unsigned int)F[8*g+0] | ((unsigned int)F[8*g+1] << 16);
    u.y = (unsigned int)F[8*g+2] | ((unsigned int)F[8*g+3] << 16);
    u.z = (unsigned int)F[8*g+4] | ((unsigned int)F[8*g+5] << 16);
    u.w = (unsigned int)F[8*g+6] | ((unsigned int)F[8*g+7] << 16);
    afrag[T * 64 + lane] = u;

    if (lane < 48) {
        const int g2 = lane / 12, idx = lane % 12;
        const int comp = idx >> 2, r = idx & 3;
        const int c2 = T * 16 + g2 * 4 + r;
        float v = 0.f;  // padded centers get coeff 0 -> contribute nothing
        if (c2 < M)
            v = (comp == 0) ? cu[c2] : ((comp == 1) ? cv[c2] : cw[c2]);
        bpack[(T * 12 + g2 * 3 + comp) * 4 + r] = v;
    }
}

// Block = 256 thr = 4 waves; block owns 32 points (2 x 16-pt MFMA tiles).
// Wave w handles center tiles [w*per, (w+1)*per); LDS reduce across waves.
// grid = N/32 = 3125 blocks -> 12500 waves (48.8/CU demanded, ~67% achieved).
__global__ __launch_bounds__(256) void rbf_main(
        const float* __restrict__ x,
        const uint4* __restrict__ afrag,
        const float4* __restrict__ bpack4,
        float* __restrict__ out, int N, int NT) {
    __shared__ float acc[NW][32][3];

    const int tid = threadIdx.x;
    const int lane = tid & 63;
    const int w = __builtin_amdgcn_readfirstlane(tid >> 6);  // wave id
    const int col = lane & 15, g = lane >> 4;
    const int pb = blockIdx.x * (16 * PT);

    float xx[PT], xy[PT], xz[PT];
    bf16x8 bfrag[PT];
#pragma unroll
    for (int t = 0; t < PT; ++t) {
        const int p = pb + t * 16 + col;
        float a0 = 0.f, a1 = 0.f, a2 = 0.f;
        if (p < N) { a0 = x[3*p]; a1 = x[3*p+1]; a2 = x[3*p+2]; }
        xx[t] = a0; xy[t] = a1; xz[t] = a2;
        const float px = -S2 * (a0*a0 + a1*a1 + a2*a2);
        // B-fragment: col=lane&15=point, k=8*(lane>>4)+e. Point features:
        // [xh,xl,xh, yh,yl,yh, zh,zl,zh, 1,1, PXh,PXl, 0,0,0]
        const unsigned short xh = bhi(a0), yh = bhi(a1), zh = bhi(a2);
        const unsigned short xl = bhi(a0 - bf2f(xh));
        const unsigned short yl = bhi(a1 - bf2f(yh));
        const unsigned short zl = bhi(a2 - bf2f(zh));
        const unsigned short ph = bhi(px), pl = bhi(px - bf2f(ph));
        unsigned int b0 = 0, b1 = 0, b2 = 0, b3 = 0;
        if (g == 0) {            // k = 0..7
            b0 = (unsigned int)xh | ((unsigned int)xl << 16);
            b1 = (unsigned int)xh | ((unsigned int)yh << 16);
            b2 = (unsigned int)yl | ((unsigned int)yh << 16);
            b3 = (unsigned int)zh | ((unsigned int)zl << 16);
        } else if (g == 1) {     // k = 8..15
            b0 = (unsigned int)zh | ((unsigned int)ONEB << 16);
            b1 = (unsigned int)ONEB | ((unsigned int)ph << 16);
            b2 = (unsigned int)pl;  // (pl, 0)
            b3 = 0;
        }                         // g = 2,3: zero (k = 16..31 unused)
        uint4 bu_;
        bu_.x = b0; bu_.y = b1; bu_.z = b2; bu_.w = b3;
        bfrag[t] = __builtin_bit_cast(bf16x8, bu_);
    }

    const f32x4 zero = {0.f, 0.f, 0.f, 0.f};
    f2 AU[PT], AV[PT], AW[PT];
#pragma unroll
    for (int t = 0; t < PT; ++t) {
        AU[t] = (f2){0.f, 0.f}; AV[t] = (f2){0.f, 0.f}; AW[t] = (f2){0.f, 0.f};
    }

    const uint4* __restrict__ ap = afrag + lane;        // coalesced stream
    const float4* __restrict__ bp = bpack4 + g * 3;     // per-group 48B line

    // wave w owns center tiles [jb, je)
    const int per = (NT + NW - 1) / NW;
    const int jb = w * per;
    const int je = min(jb + per, NT);

#pragma unroll 4
    for (int T = jb; T < je; ++T) {
        const uint4 a = ap[T * 64];
        const float4 bu = bp[T * 12 + 0];
        const float4 bv = bp[T * 12 + 1];
        const float4 bw = bp[T * 12 + 2];
        const bf16x8 af = __builtin_bit_cast(bf16x8, a);
        const f2 BU01 = {bu.x, bu.y}, BU23 = {bu.z, bu.w};
        const f2 BV01 = {bv.x, bv.y}, BV23 = {bv.z, bv.w};
        const f2 BW01 = {bw.x, bw.y}, BW23 = {bw.z, bw.w};
#pragma unroll
        for (int t = 0; t < PT; ++t) {
            const f32x4 E = __builtin_amdgcn_mfma_f32_16x16x32_bf16(
                af, bfrag[t], zero, 0, 0, 0);
            f2 P01, P23;
            P01.x = __builtin_amdgcn_exp2f(E[0]);
            P01.y = __builtin_amdgcn_exp2f(E[1]);
            P23.x = __builtin_amdgcn_exp2f(E[2]);
            P23.y = __builtin_amdgcn_exp2f(E[3]);
            AU[t] += P01 * BU01; AU[t] += P23 * BU23;  // v_pk_fma_f32
            AV[t] += P01 * BV01; AV[t] += P23 * BV23;
            AW[t] += P01 * BW01; AW[t] += P23 * BW23;
        }
    }

    float au[PT], av[PT], aw[PT];
#pragma unroll
    for (int t = 0; t < PT; ++t) {
        au[t] = AU[t].x + AU[t].y;
        av[t] = AV[t].x + AV[t].y;
        aw[t] = AW[t].x + AW[t].y;
        // Reduce over the 4 lane groups g (centers {16T + 4g + r}).
        au[t] += __shfl_xor(au[t], 16); au[t] += __shfl_xor(au[t], 32);
        av[t] += __shfl_xor(av[t], 16); av[t] += __shfl_xor(av[t], 32);
        aw[t] += __shfl_xor(aw[t], 16); aw[t] += __shfl_xor(aw[t], 32);
    }

    // Base field once per point: wave 0 only.
    if (w == 0 && g == 0) {
#pragma unroll
        for (int t = 0; t < PT; ++t) {
            const float r = sqrtf(xx[t]*xx[t] + xy[t]*xy[t] + xz[t]*xz[t]);
            const float s = 1.f - r;
            au[t] = fmaf(xx[t], s, au[t]);
            av[t] = fmaf(xy[t], s, av[t]);
            aw[t] = fmaf(xz[t], s, aw[t]);
        }
    }

    if (g == 0) {
#pragma unroll
        for (int t = 0; t < PT; ++t) {
            acc[w][t * 16 + col][0] = au[t];
            acc[w][t * 16 + col][1] = av[t];
            acc[w][t * 16 + col][2] = aw[t];
        }
    }
    __syncthreads();

    // 96 outputs per block, stride-1 across tid -> coalesced store.
    if (tid < 96) {
        const int gi = pb * 3 + tid;
        if (gi < 3 * N) {
            const int pl = tid / 3, c = tid % 3;
            out[gi] = acc[0][pl][c] + acc[1][pl][c] +
                      acc[2][pl][c] + acc[3][pl][c];
        }
    }
}

extern "C" void kernel_launch(void* const* d_in, const int* in_sizes, int n_in,
                              void* d_out, int out_size, void* d_ws,
                              size_t ws_size, hipStream_t stream) {
    const float* x = (const float*)d_in[0];
    const float* centers = (const float*)d_in[1];
    const float* cu = (const float*)d_in[2];
    const float* cv = (const float*)d_in[3];
    const float* cw = (const float*)d_in[4];
    float* out = (float*)d_out;
    const int N = in_sizes[0] / 3;
    const int M = in_sizes[1] / 3;
    const int NT = (M + 15) / 16;

    uint4* afrag = (uint4*)d_ws;                              // NT*1024 B
    float* bpack = (float*)((char*)d_ws + (size_t)NT * 1024); // NT*192 B

    hipLaunchKernelGGL(rbf_prep, dim3(NT), dim3(64), 0, stream,
                       centers, cu, cv, cw, afrag, bpack, M);
    hipLaunchKernelGGL(rbf_main, dim3((N + 16 * PT - 1) / (16 * PT)),
                       dim3(256), 0, stream,
                       x, afrag, (const float4*)bpack, out, N, NT);
}

// Round 8
// 127.456 us; speedup vs baseline: 1.1517x; 1.1402x over previous
//
#include <hip/hip_runtime.h>

// phi = exp2(-S2*d2), S2 = 1/(2*ls^2*ln2) = 8.014973
// e = 2*S2*(x.c) - S2*|c|^2 - S2*|x|^2  =  a1*x + a2*y + a3*z + a4*1 + 1*PX
// via mfma_f32_16x16x32_bf16, split-bf16 (hi + residual-lo) features.
// SWAPPED operands (A=centers, B=points): D layout col=lane&15=point,
// row=(lane>>4)*4+reg=center -> exp2 + fp32 PV accumulation lane-local.
// R8: b-coefficients staged in LDS (40.5 KB/block, once) -- R5/R6/R7 all
// pinned busy≈48us but elapsed 80-97us with idle GROWING with wave count:
// shared-resource congestion, diagnosed as L1/TA port saturated by the 3
// broadcast b-loads/iter (1KB through L1 for 48 useful bytes each) + the
// streaming 1KB a-load thrashing 32KB L1. Now 1 VMEM/iter; b on LDS pipe.
// Shape: PT=4 (R5's 340cy body) x NW=8 (R7's 12500 waves), 1563 blocks.
#define S2 8.014973f
#define K2 16.029946f
#define ONEB ((unsigned short)0x3F80)  // bf16(1.0)
#define PT 4     // 16-point MFMA tiles per block (64 points)
#define NW 8     // waves per block (center-split ways)
#define NTMAX 212

typedef float f32x4 __attribute__((ext_vector_type(4)));
typedef float f2 __attribute__((ext_vector_type(2)));
typedef short bf16x8 __attribute__((ext_vector_type(8)));

__device__ __forceinline__ unsigned short bhi(float v) {  // RNE f32->bf16
    unsigned int b = __builtin_bit_cast(unsigned int, v);
    return (unsigned short)((b + 0x7FFFu + ((b >> 16) & 1u)) >> 16);
}
__device__ __forceinline__ float bf2f(unsigned short h) {
    unsigned int u = ((unsigned int)h) << 16;
    return __builtin_bit_cast(float, u);
}

// One block (1 wave) per 16-center tile T: writes
//  afrag[T*64+lane] = A-fragment uint4 (8 bf16): row=lane&15, k=8*(lane>>4)+e
//  bpack[(T*12 + g*3 + comp)*4 + r] = coeff[comp][16T+4g+r] (D-layout floats)
__global__ void rbf_prep(const float* __restrict__ centers,
                         const float* __restrict__ cu,
                         const float* __restrict__ cv,
                         const float* __restrict__ cw,
                         uint4* __restrict__ afrag,
                         float* __restrict__ bpack, int M) {
    const int T = blockIdx.x;
    const int lane = threadIdx.x;
    const int row = lane & 15, g = lane >> 4;
    const int c = T * 16 + row;
    float cx = 0.f, cy = 0.f, cz = 0.f;
    if (c < M) { cx = centers[3*c]; cy = centers[3*c+1]; cz = centers[3*c+2]; }
    const float a1 = K2 * cx, a2 = K2 * cy, a3 = K2 * cz;
    const float a4 = -S2 * (cx*cx + cy*cy + cz*cz);
    const unsigned short a1h = bhi(a1), a2h = bhi(a2), a3h = bhi(a3), a4h = bhi(a4);
    const unsigned short a1l = bhi(a1 - bf2f(a1h));
    const unsigned short a2l = bhi(a2 - bf2f(a2h));
    const unsigned short a3l = bhi(a3 - bf2f(a3h));
    const unsigned short a4l = bhi(a4 - bf2f(a4h));
    const unsigned short F[16] = {a1h, a1h, a1l, a2h, a2h, a2l, a3h, a3h,
                                  a3l, a4h, a4l, ONEB, ONEB, 0, 0, 0};
    uint4 u;  // prep is tiny; scratch from dynamic F index is fine here
    u.x = (unsigned int)F[8*g+0] | ((unsigned int)F[8*g+1] << 16);
    u.y = (unsigned int)F[8*g+2] | ((unsigned int)F[8*g+3] << 16);
    u.z = (unsigned int)F[8*g+4] | ((unsigned int)F[8*g+5] << 16);
    u.w = (unsigned int)F[8*g+6] | ((unsigned int)F[8*g+7] << 16);
    afrag[T * 64 + lane] = u;

    if (lane < 48) {
        const int g2 = lane / 12, idx = lane % 12;
        const int comp = idx >> 2, r = idx & 3;
        const int c2 = T * 16 + g2 * 4 + r;
        float v = 0.f;  // padded centers get coeff 0 -> contribute nothing
        if (c2 < M)
            v = (comp == 0) ? cu[c2] : ((comp == 1) ? cv[c2] : cw[c2]);
        bpack[(T * 12 + g2 * 3 + comp) * 4 + r] = v;
    }
}

// Block = 512 thr = 8 waves; block owns 64 points (4 x 16-pt MFMA tiles).
// bpack staged to LDS once (all NT tiles; waves cover disjoint ranges).
// Wave w handles center tiles [w*per, ...); LDS reduce across waves at end.
// grid = N/64 = 1563 blocks -> 12504 waves; LDS 46.8KB -> 3 blocks/CU.
__global__ __launch_bounds__(512) void rbf_main(
        const float* __restrict__ x,
        const uint4* __restrict__ afrag,
        const float4* __restrict__ bpack4,
        float* __restrict__ out, int N, int NT) {
    __shared__ float4 bl[NTMAX * 12];          // 40704 B
    __shared__ float acc[NW][16 * PT][3];      // 6144 B

    const int tid = threadIdx.x;
    const int lane = tid & 63;
    const int w = __builtin_amdgcn_readfirstlane(tid >> 6);  // wave id
    const int col = lane & 15, g = lane >> 4;
    const int pb = blockIdx.x * (16 * PT);

    // Stage all b-coefficients to LDS (coalesced float4 stream).
    const int nb = NT * 12;
    for (int i = tid; i < nb; i += 64 * NW) bl[i] = bpack4[i];

    float xx[PT], xy[PT], xz[PT];
    bf16x8 bfrag[PT];
#pragma unroll
    for (int t = 0; t < PT; ++t) {
        const int p = pb + t * 16 + col;
        float a0 = 0.f, a1 = 0.f, a2 = 0.f;
        if (p < N) { a0 = x[3*p]; a1 = x[3*p+1]; a2 = x[3*p+2]; }
        xx[t] = a0; xy[t] = a1; xz[t] = a2;
        const float px = -S2 * (a0*a0 + a1*a1 + a2*a2);
        // B-fragment: col=lane&15=point, k=8*(lane>>4)+e. Point features:
        // [xh,xl,xh, yh,yl,yh, zh,zl,zh, 1,1, PXh,PXl, 0,0,0]
        const unsigned short xh = bhi(a0), yh = bhi(a1), zh = bhi(a2);
        const unsigned short xl = bhi(a0 - bf2f(xh));
        const unsigned short yl = bhi(a1 - bf2f(yh));
        const unsigned short zl = bhi(a2 - bf2f(zh));
        const unsigned short ph = bhi(px), pl = bhi(px - bf2f(ph));
        unsigned int b0 = 0, b1 = 0, b2 = 0, b3 = 0;
        if (g == 0) {            // k = 0..7
            b0 = (unsigned int)xh | ((unsigned int)xl << 16);
            b1 = (unsigned int)xh | ((unsigned int)yh << 16);
            b2 = (unsigned int)yl | ((unsigned int)yh << 16);
            b3 = (unsigned int)zh | ((unsigned int)zl << 16);
        } else if (g == 1) {     // k = 8..15
            b0 = (unsigned int)zh | ((unsigned int)ONEB << 16);
            b1 = (unsigned int)ONEB | ((unsigned int)ph << 16);
            b2 = (unsigned int)pl;  // (pl, 0)
            b3 = 0;
        }                         // g = 2,3: zero (k = 16..31 unused)
        uint4 bu_;
        bu_.x = b0; bu_.y = b1; bu_.z = b2; bu_.w = b3;
        bfrag[t] = __builtin_bit_cast(bf16x8, bu_);
    }

    const f32x4 zero = {0.f, 0.f, 0.f, 0.f};
    f2 AU[PT], AV[PT], AW[PT];
#pragma unroll
    for (int t = 0; t < PT; ++t) {
        AU[t] = (f2){0.f, 0.f}; AV[t] = (f2){0.f, 0.f}; AW[t] = (f2){0.f, 0.f};
    }

    const uint4* __restrict__ ap = afrag + lane;  // coalesced 1KB/iter stream

    // wave w owns center tiles [jb, je)
    const int per = (NT + NW - 1) / NW;
    const int jb = w * per;
    const int je = min(jb + per, NT);

    __syncthreads();   // staging complete

#pragma unroll 2
    for (int T = jb; T < je; ++T) {
        const uint4 a = ap[T * 64];              // the ONLY VMEM in the loop
        const float4 bu = bl[T * 12 + g * 3 + 0];  // ds_read_b128, 4-addr
        const float4 bv = bl[T * 12 + g * 3 + 1];  //   broadcast: conflict-free
        const float4 bw = bl[T * 12 + g * 3 + 2];
        const bf16x8 af = __builtin_bit_cast(bf16x8, a);
        const f2 BU01 = {bu.x, bu.y}, BU23 = {bu.z, bu.w};
        const f2 BV01 = {bv.x, bv.y}, BV23 = {bv.z, bv.w};
        const f2 BW01 = {bw.x, bw.y}, BW23 = {bw.z, bw.w};
#pragma unroll
        for (int t = 0; t < PT; ++t) {
            const f32x4 E = __builtin_amdgcn_mfma_f32_16x16x32_bf16(
                af, bfrag[t], zero, 0, 0, 0);
            f2 P01, P23;
            P01.x = __builtin_amdgcn_exp2f(E[0]);
            P01.y = __builtin_amdgcn_exp2f(E[1]);
            P23.x = __builtin_amdgcn_exp2f(E[2]);
            P23.y = __builtin_amdgcn_exp2f(E[3]);
            AU[t] += P01 * BU01; AU[t] += P23 * BU23;  // v_pk_fma_f32
            AV[t] += P01 * BV01; AV[t] += P23 * BV23;
            AW[t] += P01 * BW01; AW[t] += P23 * BW23;
        }
    }

    float au[PT], av[PT], aw[PT];
#pragma unroll
    for (int t = 0; t < PT; ++t) {
        au[t] = AU[t].x + AU[t].y;
        av[t] = AV[t].x + AV[t].y;
        aw[t] = AW[t].x + AW[t].y;
        // Reduce over the 4 lane groups g (centers {16T + 4g + r}).
        au[t] += __shfl_xor(au[t], 16); au[t] += __shfl_xor(au[t], 32);
        av[t] += __shfl_xor(av[t], 16); av[t] += __shfl_xor(av[t], 32);
        aw[t] += __shfl_xor(aw[t], 16); aw[t] += __shfl_xor(aw[t], 32);
    }

    // Base field once per point: wave 0 only.
    if (w == 0 && g == 0) {
#pragma unroll
        for (int t = 0; t < PT; ++t) {
            const float r = sqrtf(xx[t]*xx[t] + xy[t]*xy[t] + xz[t]*xz[t]);
            const float s = 1.f - r;
            au[t] = fmaf(xx[t], s, au[t]);
            av[t] = fmaf(xy[t], s, av[t]);
            aw[t] = fmaf(xz[t], s, aw[t]);
        }
    }

    if (g == 0) {
#pragma unroll
        for (int t = 0; t < PT; ++t) {
            acc[w][t * 16 + col][0] = au[t];
            acc[w][t * 16 + col][1] = av[t];
            acc[w][t * 16 + col][2] = aw[t];
        }
    }
    __syncthreads();

    // 192 outputs per block, stride-1 across tid -> coalesced store.
    if (tid < 192) {
        const int gi = pb * 3 + tid;
        if (gi < 3 * N) {
            const int pl = tid / 3, c = tid % 3;
            float s = 0.f;
#pragma unroll
            for (int k = 0; k < NW; ++k) s += acc[k][pl][c];
            out[gi] = s;
        }
    }
}

extern "C" void kernel_launch(void* const* d_in, const int* in_sizes, int n_in,
                              void* d_out, int out_size, void* d_ws,
                              size_t ws_size, hipStream_t stream) {
    const float* x = (const float*)d_in[0];
    const float* centers = (const float*)d_in[1];
    const float* cu = (const float*)d_in[2];
    const float* cv = (const float*)d_in[3];
    const float* cw = (const float*)d_in[4];
    float* out = (float*)d_out;
    const int N = in_sizes[0] / 3;
    const int M = in_sizes[1] / 3;
    const int NT = (M + 15) / 16;

    uint4* afrag = (uint4*)d_ws;                              // NT*1024 B
    float* bpack = (float*)((char*)d_ws + (size_t)NT * 1024); // NT*192 B

    hipLaunchKernelGGL(rbf_prep, dim3(NT), dim3(64), 0, stream,
                       centers, cu, cv, cw, afrag, bpack, M);
    hipLaunchKernelGGL(rbf_main, dim3((N + 16 * PT - 1) / (16 * PT)),
                       dim3(64 * NW), 0, stream,
                       x, afrag, (const float4*)bpack, out, N, NT);
}